// Round 2
// baseline (12614.975 us; speedup 1.0000x reference)
//
#include <hip/hip_runtime.h>
#include <math.h>

#define N_NODES 100000
#define N_BASE  5000
#define N_EDGES 3200000

// ---------------------------------------------------------------------------
// k_init: deg[i] = 1 (self loop), zero the scalar accumulator
// ---------------------------------------------------------------------------
__global__ __launch_bounds__(256) void k_init(float* __restrict__ deg, float* __restrict__ sumb) {
    int i = blockIdx.x * 256 + threadIdx.x;
    if (i < N_NODES) deg[i] = 1.0f;
    if (i == 0) sumb[0] = 0.0f;
}

// deg[col[e]] += 1
__global__ __launch_bounds__(256) void k_count(const int* __restrict__ col, float* __restrict__ deg) {
    int e = blockIdx.x * 256 + threadIdx.x;
    if (e < N_EDGES) atomicAdd(&deg[col[e]], 1.0f);
}

// deg -> deg^-0.5 in place
__global__ __launch_bounds__(256) void k_dinv(float* __restrict__ deg) {
    int i = blockIdx.x * 256 + threadIdx.x;
    if (i < N_NODES) deg[i] = rsqrtf(deg[i]);
}

// norm[e] = dinv[row[e]] * dinv[col[e]]
__global__ __launch_bounds__(256) void k_norm(const int* __restrict__ row, const int* __restrict__ col,
                                              const float* __restrict__ dinv, float* __restrict__ normE) {
    int e = blockIdx.x * 256 + threadIdx.x;
    if (e < N_EDGES) normE[e] = dinv[row[e]] * dinv[col[e]];
}

// ---------------------------------------------------------------------------
// k_ab: b = [x1 | tile(x2)] @ W4^T + b4   (stride 20)
//       a = relu(x1 @ W1^T + b1)          (stride 16, a[15]=0)
// ---------------------------------------------------------------------------
__global__ __launch_bounds__(256) void k_ab(const float* __restrict__ x1, const float* __restrict__ x2,
                                            const float* __restrict__ W1, const float* __restrict__ b1,
                                            const float* __restrict__ W4, const float* __restrict__ b4,
                                            float* __restrict__ a, float* __restrict__ bb) {
    __shared__ float sW1[225], sb1[15], sW4[361], sb4[19];
    for (int t = threadIdx.x; t < 225; t += 256) sW1[t] = W1[t];
    for (int t = threadIdx.x; t < 361; t += 256) sW4[t] = W4[t];
    if (threadIdx.x < 15) sb1[threadIdx.x] = b1[threadIdx.x];
    if (threadIdx.x < 19) sb4[threadIdx.x] = b4[threadIdx.x];
    __syncthreads();
    int i = blockIdx.x * 256 + threadIdx.x;
    if (i >= N_NODES) return;
    float in[19];
#pragma unroll
    for (int k = 0; k < 15; k++) in[k] = x1[(size_t)i * 15 + k];
    int ib = i % N_BASE;
#pragma unroll
    for (int k = 0; k < 4; k++) in[15 + k] = x2[(size_t)ib * 4 + k];
#pragma unroll
    for (int o = 0; o < 19; o++) {
        float s = sb4[o];
#pragma unroll
        for (int k = 0; k < 19; k++) s += in[k] * sW4[o * 19 + k];
        bb[(size_t)i * 20 + o] = s;
    }
#pragma unroll
    for (int o = 0; o < 15; o++) {
        float s = sb1[o];
#pragma unroll
        for (int k = 0; k < 15; k++) s += in[k] * sW1[o * 15 + k];
        a[(size_t)i * 16 + o] = fmaxf(s, 0.0f);
    }
    a[(size_t)i * 16 + 15] = 0.0f;
}

// ---------------------------------------------------------------------------
// k_h: a_i = (first) ? a[i] : relu(agg[i]+bg)   (fused relu from prev iter)
//      h[i] = Wg @ [a_i | b_i]                  (stride 16, h[15]=0)
//      agg[i] = h[i] * dinv[i]^2                (self-loop contribution)
// ---------------------------------------------------------------------------
__global__ __launch_bounds__(256) void k_h(const float* __restrict__ a, float* __restrict__ agg,
                                           const float* __restrict__ bb, const float* __restrict__ Wg,
                                           const float* __restrict__ bg, const float* __restrict__ dinv,
                                           float* __restrict__ h, int first) {
    __shared__ float sW[510], sbg[15];
    for (int t = threadIdx.x; t < 510; t += 256) sW[t] = Wg[t];
    if (threadIdx.x < 15) sbg[threadIdx.x] = bg[threadIdx.x];
    __syncthreads();
    int i = blockIdx.x * 256 + threadIdx.x;
    if (i >= N_NODES) return;
    float in[34];
    if (first) {
#pragma unroll
        for (int k = 0; k < 15; k++) in[k] = a[(size_t)i * 16 + k];
    } else {
#pragma unroll
        for (int k = 0; k < 15; k++) in[k] = fmaxf(agg[(size_t)i * 16 + k] + sbg[k], 0.0f);
    }
#pragma unroll
    for (int k = 0; k < 19; k++) in[15 + k] = bb[(size_t)i * 20 + k];
    float dn = dinv[i];
    float self = dn * dn;
#pragma unroll
    for (int o = 0; o < 15; o++) {
        float s = 0.0f;
#pragma unroll
        for (int k = 0; k < 34; k++) s += in[k] * sW[o * 34 + k];
        h[(size_t)i * 16 + o] = s;
        agg[(size_t)i * 16 + o] = s * self;
    }
    h[(size_t)i * 16 + 15] = 0.0f;
    agg[(size_t)i * 16 + 15] = 0.0f;
}

// ---------------------------------------------------------------------------
// k_scatter: agg[col[e]] += h[row[e]] * norm[e]   (15 f32 atomics per edge)
// ---------------------------------------------------------------------------
__global__ __launch_bounds__(256) void k_scatter(const int* __restrict__ row, const int* __restrict__ col,
                                                 const float* __restrict__ normE, const float* __restrict__ h,
                                                 float* __restrict__ agg) {
    int e = blockIdx.x * 256 + threadIdx.x;
    if (e >= N_EDGES) return;
    int s = row[e], d = col[e];
    float nrm = normE[e];
    const float4* hs = (const float4*)(h + (size_t)s * 16);
    float4 h0 = hs[0], h1 = hs[1], h2 = hs[2], h3 = hs[3];
    float* ad = agg + (size_t)d * 16;
    atomicAdd(ad + 0,  h0.x * nrm);
    atomicAdd(ad + 1,  h0.y * nrm);
    atomicAdd(ad + 2,  h0.z * nrm);
    atomicAdd(ad + 3,  h0.w * nrm);
    atomicAdd(ad + 4,  h1.x * nrm);
    atomicAdd(ad + 5,  h1.y * nrm);
    atomicAdd(ad + 6,  h1.z * nrm);
    atomicAdd(ad + 7,  h1.w * nrm);
    atomicAdd(ad + 8,  h2.x * nrm);
    atomicAdd(ad + 9,  h2.y * nrm);
    atomicAdd(ad + 10, h2.z * nrm);
    atomicAdd(ad + 11, h2.w * nrm);
    atomicAdd(ad + 12, h3.x * nrm);
    atomicAdd(ad + 13, h3.y * nrm);
    atomicAdd(ad + 14, h3.z * nrm);
}

// ---------------------------------------------------------------------------
// k_final: per-node out_i = W3 @ [relu(agg+bg) | b], block-reduce, atomic sum
// ---------------------------------------------------------------------------
__global__ __launch_bounds__(256) void k_final(const float* __restrict__ agg, const float* __restrict__ bb,
                                               const float* __restrict__ W3, const float* __restrict__ bg,
                                               float* __restrict__ sumb) {
    __shared__ float sW[34], sbg[15];
    if (threadIdx.x < 34) sW[threadIdx.x] = W3[threadIdx.x];
    if (threadIdx.x < 15) sbg[threadIdx.x] = bg[threadIdx.x];
    __syncthreads();
    int i = blockIdx.x * 256 + threadIdx.x;
    float val = 0.0f;
    if (i < N_NODES) {
        float s = 0.0f;
#pragma unroll
        for (int k = 0; k < 15; k++) s += fmaxf(agg[(size_t)i * 16 + k] + sbg[k], 0.0f) * sW[k];
#pragma unroll
        for (int k = 0; k < 19; k++) s += bb[(size_t)i * 20 + k] * sW[15 + k];
        val = s;
    }
#pragma unroll
    for (int off = 32; off > 0; off >>= 1) val += __shfl_down(val, off, 64);
    __shared__ float wsum[4];
    if ((threadIdx.x & 63) == 0) wsum[threadIdx.x >> 6] = val;
    __syncthreads();
    if (threadIdx.x == 0) atomicAdd(sumb, wsum[0] + wsum[1] + wsum[2] + wsum[3]);
}

__global__ void k_finalize(const float* __restrict__ sumb, const float* __restrict__ b3,
                           float* __restrict__ out) {
    out[0] = tanhf(sumb[0] * (1.0f / (float)N_NODES) + b3[0]);
}

// ---------------------------------------------------------------------------
extern "C" void kernel_launch(void* const* d_in, const int* in_sizes, int n_in,
                              void* d_out, int out_size, void* d_ws, size_t ws_size,
                              hipStream_t stream) {
    const float* x1 = (const float*)d_in[0];
    const float* x2 = (const float*)d_in[1];
    const int* edges = (const int*)d_in[2];
    const float* W1 = (const float*)d_in[3];
    const float* b1 = (const float*)d_in[4];
    const float* Wg = (const float*)d_in[5];
    const float* bg = (const float*)d_in[6];
    const float* W3 = (const float*)d_in[7];
    const float* b3 = (const float*)d_in[8];
    const float* W4 = (const float*)d_in[9];
    const float* b4 = (const float*)d_in[10];

    const int* row = edges;             // edges[0]
    const int* col = edges + N_EDGES;   // edges[1]

    // workspace layout (floats)
    float* ws    = (float*)d_ws;
    float* deg   = ws;                                  // N      (becomes dinv)
    float* normE = deg + N_NODES;                       // E
    float* a     = normE + N_EDGES;                     // N*16
    float* bb    = a + (size_t)N_NODES * 16;            // N*20
    float* h     = bb + (size_t)N_NODES * 20;           // N*16
    float* agg   = h + (size_t)N_NODES * 16;            // N*16
    float* sumb  = agg + (size_t)N_NODES * 16;          // 1

    int gN = (N_NODES + 255) / 256;
    int gE = (N_EDGES + 255) / 256;

    k_init<<<gN, 256, 0, stream>>>(deg, sumb);
    k_count<<<gE, 256, 0, stream>>>(col, deg);
    k_dinv<<<gN, 256, 0, stream>>>(deg);
    k_norm<<<gE, 256, 0, stream>>>(row, col, deg, normE);
    k_ab<<<gN, 256, 0, stream>>>(x1, x2, W1, b1, W4, b4, a, bb);
    for (int t = 0; t < 5; t++) {
        k_h<<<gN, 256, 0, stream>>>(a, agg, bb, Wg, bg, deg, h, t == 0 ? 1 : 0);
        k_scatter<<<gE, 256, 0, stream>>>(row, col, normE, h, agg);
    }
    k_final<<<gN, 256, 0, stream>>>(agg, bb, W3, bg, sumb);
    k_finalize<<<1, 1, 0, stream>>>(sumb, b3, (float*)d_out);
}

// Round 3
// 1148.924 us; speedup vs baseline: 10.9798x; 10.9798x over previous
//
#include <hip/hip_runtime.h>
#include <math.h>

#define N_NODES 100000
#define N_BASE  5000
#define N_EDGES 3200000

// ---------------------------------------------------------------------------
// k_init0: zero deg + cursor + scalar accumulator
// ---------------------------------------------------------------------------
__global__ __launch_bounds__(256) void k_init0(int* __restrict__ deg, int* __restrict__ cursor,
                                               float* __restrict__ sumb) {
    int i = blockIdx.x * 256 + threadIdx.x;
    if (i < N_NODES) { deg[i] = 0; cursor[i] = 0; }
    if (i == 0) sumb[0] = 0.0f;
}

// deg[col[e]] += 1 (int atomics, once)
__global__ __launch_bounds__(256) void k_count(const int* __restrict__ col, int* __restrict__ deg) {
    int e = blockIdx.x * 256 + threadIdx.x;
    if (e < N_EDGES) atomicAdd(&deg[col[e]], 1);
}

// ---------------------------------------------------------------------------
// k_scan: single-block exclusive scan deg -> rowptr, fused dinv = rsqrt(deg+1)
// ---------------------------------------------------------------------------
__global__ __launch_bounds__(1024) void k_scan(const int* __restrict__ deg, int* __restrict__ rowptr,
                                               float* __restrict__ dinv) {
    __shared__ int part[1024];
    const int CH = (N_NODES + 1023) / 1024;  // 98
    int t = threadIdx.x;
    int lo = t * CH;
    int hi = lo + CH; if (hi > N_NODES) hi = N_NODES; if (lo > N_NODES) lo = N_NODES;
    int s = 0;
    for (int i = lo; i < hi; i++) s += deg[i];
    part[t] = s;
    __syncthreads();
    // Hillis-Steele inclusive scan over 1024 partials
    for (int off = 1; off < 1024; off <<= 1) {
        int v = (t >= off) ? part[t - off] : 0;
        __syncthreads();
        part[t] += v;
        __syncthreads();
    }
    int run = part[t] - s;  // exclusive prefix for this chunk
    for (int i = lo; i < hi; i++) {
        rowptr[i] = run;
        run += deg[i];
        dinv[i] = rsqrtf((float)(deg[i] + 1));  // +1 self loop
    }
    if (t == 1023) rowptr[N_NODES] = run;  // == N_EDGES
}

// ---------------------------------------------------------------------------
// k_fill: scatter edge sources into CSR slots grouped by destination
// ---------------------------------------------------------------------------
__global__ __launch_bounds__(256) void k_fill(const int* __restrict__ row, const int* __restrict__ col,
                                              const int* __restrict__ rowptr, int* __restrict__ cursor,
                                              int* __restrict__ csr_src) {
    int e = blockIdx.x * 256 + threadIdx.x;
    if (e >= N_EDGES) return;
    int d = col[e];
    int pos = rowptr[d] + atomicAdd(&cursor[d], 1);
    csr_src[pos] = row[e];
}

// ---------------------------------------------------------------------------
// k_ab: b = [x1 | tile(x2)] @ W4^T + b4   (stride 20)
//       a = relu(x1 @ W1^T + b1)          (stride 16, a[15]=0)
// ---------------------------------------------------------------------------
__global__ __launch_bounds__(256) void k_ab(const float* __restrict__ x1, const float* __restrict__ x2,
                                            const float* __restrict__ W1, const float* __restrict__ b1,
                                            const float* __restrict__ W4, const float* __restrict__ b4,
                                            float* __restrict__ a, float* __restrict__ bb) {
    __shared__ float sW1[225], sb1[15], sW4[361], sb4[19];
    for (int t = threadIdx.x; t < 225; t += 256) sW1[t] = W1[t];
    for (int t = threadIdx.x; t < 361; t += 256) sW4[t] = W4[t];
    if (threadIdx.x < 15) sb1[threadIdx.x] = b1[threadIdx.x];
    if (threadIdx.x < 19) sb4[threadIdx.x] = b4[threadIdx.x];
    __syncthreads();
    int i = blockIdx.x * 256 + threadIdx.x;
    if (i >= N_NODES) return;
    float in[19];
#pragma unroll
    for (int k = 0; k < 15; k++) in[k] = x1[(size_t)i * 15 + k];
    int ib = i % N_BASE;
#pragma unroll
    for (int k = 0; k < 4; k++) in[15 + k] = x2[(size_t)ib * 4 + k];
#pragma unroll
    for (int o = 0; o < 19; o++) {
        float s = sb4[o];
#pragma unroll
        for (int k = 0; k < 19; k++) s += in[k] * sW4[o * 19 + k];
        bb[(size_t)i * 20 + o] = s;
    }
#pragma unroll
    for (int o = 0; o < 15; o++) {
        float s = sb1[o];
#pragma unroll
        for (int k = 0; k < 15; k++) s += in[k] * sW1[o * 15 + k];
        a[(size_t)i * 16 + o] = fmaxf(s, 0.0f);
    }
    a[(size_t)i * 16 + 15] = 0.0f;
}

// ---------------------------------------------------------------------------
// k_h: a_i = (first) ? a[i] : relu(agg[i]+bg)
//      h'[i] = dinv[i] * (Wg @ [a_i | b_i])   (stride 16, h'[15]=0)
// dinv folded into h so the gather needs no per-edge norm at all.
// ---------------------------------------------------------------------------
__global__ __launch_bounds__(256) void k_h(const float* __restrict__ a, const float* __restrict__ agg,
                                           const float* __restrict__ bb, const float* __restrict__ Wg,
                                           const float* __restrict__ bg, const float* __restrict__ dinv,
                                           float* __restrict__ h, int first) {
    __shared__ float sW[510], sbg[15];
    for (int t = threadIdx.x; t < 510; t += 256) sW[t] = Wg[t];
    if (threadIdx.x < 15) sbg[threadIdx.x] = bg[threadIdx.x];
    __syncthreads();
    int i = blockIdx.x * 256 + threadIdx.x;
    if (i >= N_NODES) return;
    float in[34];
    if (first) {
#pragma unroll
        for (int k = 0; k < 15; k++) in[k] = a[(size_t)i * 16 + k];
    } else {
#pragma unroll
        for (int k = 0; k < 15; k++) in[k] = fmaxf(agg[(size_t)i * 16 + k] + sbg[k], 0.0f);
    }
#pragma unroll
    for (int k = 0; k < 19; k++) in[15 + k] = bb[(size_t)i * 20 + k];
    float dn = dinv[i];
#pragma unroll
    for (int o = 0; o < 15; o++) {
        float s = 0.0f;
#pragma unroll
        for (int k = 0; k < 34; k++) s += in[k] * sW[o * 34 + k];
        h[(size_t)i * 16 + o] = s * dn;
    }
    h[(size_t)i * 16 + 15] = 0.0f;
}

// ---------------------------------------------------------------------------
// k_gather: one wave per destination node; 64 lanes = 4 edge-slots x 16 ch.
//   agg[d] = dinv[d] * (h'[d] + sum_{s in N(d)} h'[s])
// ---------------------------------------------------------------------------
__global__ __launch_bounds__(256) void k_gather(const int* __restrict__ rowptr,
                                                const int* __restrict__ csr_src,
                                                const float* __restrict__ h,
                                                const float* __restrict__ dinv,
                                                float* __restrict__ agg) {
    int node = blockIdx.x * 4 + (threadIdx.x >> 6);
    if (node >= N_NODES) return;
    int lane = threadIdx.x & 63;
    int ch = lane & 15;
    int q = lane >> 4;
    int start = rowptr[node], end = rowptr[node + 1];
    float acc = 0.0f;
    for (int j = start + q; j < end; j += 4) {
        int s = csr_src[j];                      // broadcast within 16-lane group
        acc += h[(size_t)s * 16 + ch];
    }
    acc += __shfl_xor(acc, 16, 64);
    acc += __shfl_xor(acc, 32, 64);
    if (q == 0) {
        float v = (acc + h[(size_t)node * 16 + ch]) * dinv[node];
        agg[(size_t)node * 16 + ch] = v;
    }
}

// ---------------------------------------------------------------------------
// k_final: per-node out_i = W3 @ [relu(agg+bg) | b], block-reduce, atomic sum
// ---------------------------------------------------------------------------
__global__ __launch_bounds__(256) void k_final(const float* __restrict__ agg, const float* __restrict__ bb,
                                               const float* __restrict__ W3, const float* __restrict__ bg,
                                               float* __restrict__ sumb) {
    __shared__ float sW[34], sbg[15];
    if (threadIdx.x < 34) sW[threadIdx.x] = W3[threadIdx.x];
    if (threadIdx.x < 15) sbg[threadIdx.x] = bg[threadIdx.x];
    __syncthreads();
    int i = blockIdx.x * 256 + threadIdx.x;
    float val = 0.0f;
    if (i < N_NODES) {
        float s = 0.0f;
#pragma unroll
        for (int k = 0; k < 15; k++) s += fmaxf(agg[(size_t)i * 16 + k] + sbg[k], 0.0f) * sW[k];
#pragma unroll
        for (int k = 0; k < 19; k++) s += bb[(size_t)i * 20 + k] * sW[15 + k];
        val = s;
    }
#pragma unroll
    for (int off = 32; off > 0; off >>= 1) val += __shfl_down(val, off, 64);
    __shared__ float wsum[4];
    if ((threadIdx.x & 63) == 0) wsum[threadIdx.x >> 6] = val;
    __syncthreads();
    if (threadIdx.x == 0) atomicAdd(sumb, wsum[0] + wsum[1] + wsum[2] + wsum[3]);
}

__global__ void k_finalize(const float* __restrict__ sumb, const float* __restrict__ b3,
                           float* __restrict__ out) {
    out[0] = tanhf(sumb[0] * (1.0f / (float)N_NODES) + b3[0]);
}

// ---------------------------------------------------------------------------
extern "C" void kernel_launch(void* const* d_in, const int* in_sizes, int n_in,
                              void* d_out, int out_size, void* d_ws, size_t ws_size,
                              hipStream_t stream) {
    const float* x1 = (const float*)d_in[0];
    const float* x2 = (const float*)d_in[1];
    const int* edges = (const int*)d_in[2];
    const float* W1 = (const float*)d_in[3];
    const float* b1 = (const float*)d_in[4];
    const float* Wg = (const float*)d_in[5];
    const float* bg = (const float*)d_in[6];
    const float* W3 = (const float*)d_in[7];
    const float* b3 = (const float*)d_in[8];
    const float* W4 = (const float*)d_in[9];
    const float* b4 = (const float*)d_in[10];

    const int* row = edges;             // edges[0]
    const int* col = edges + N_EDGES;   // edges[1]

    // workspace layout (4-byte words)
    char* ws = (char*)d_ws;
    int*   deg     = (int*)ws;                                  // N
    int*   cursor  = deg + N_NODES;                             // N
    int*   rowptr  = cursor + N_NODES;                          // N+1
    int*   csr_src = rowptr + (N_NODES + 1);                    // E
    float* dinv    = (float*)(csr_src + N_EDGES);               // N
    float* a       = dinv + N_NODES;                            // N*16
    float* bb      = a + (size_t)N_NODES * 16;                  // N*20
    float* h       = bb + (size_t)N_NODES * 20;                 // N*16
    float* agg     = h + (size_t)N_NODES * 16;                  // N*16
    float* sumb    = agg + (size_t)N_NODES * 16;                // 1

    int gN = (N_NODES + 255) / 256;
    int gE = (N_EDGES + 255) / 256;

    k_init0<<<gN, 256, 0, stream>>>(deg, cursor, sumb);
    k_count<<<gE, 256, 0, stream>>>(col, deg);
    k_scan<<<1, 1024, 0, stream>>>(deg, rowptr, dinv);
    k_fill<<<gE, 256, 0, stream>>>(row, col, rowptr, cursor, csr_src);
    k_ab<<<gN, 256, 0, stream>>>(x1, x2, W1, b1, W4, b4, a, bb);
    for (int t = 0; t < 5; t++) {
        k_h<<<gN, 256, 0, stream>>>(a, agg, bb, Wg, bg, dinv, h, t == 0 ? 1 : 0);
        k_gather<<<(N_NODES + 3) / 4, 256, 0, stream>>>(rowptr, csr_src, h, dinv, agg);
    }
    k_final<<<gN, 256, 0, stream>>>(agg, bb, W3, bg, sumb);
    k_finalize<<<1, 1, 0, stream>>>(sumb, b3, (float*)d_out);
}